// Round 1
// baseline (648.083 us; speedup 1.0000x reference)
//
#include <hip/hip_runtime.h>
#include <hip/hip_bf16.h>

#define PP 32000
#define DD 128
#define BBATCH 4096

typedef __bf16 bf16x8 __attribute__((ext_vector_type(8)));
typedef float f32x4 __attribute__((ext_vector_type(4)));

// RNE float -> bf16 (inputs are finite; no NaN handling needed)
__device__ __forceinline__ unsigned short f2bf(float f) {
    unsigned u = __float_as_uint(f);
    u += 0x7FFFu + ((u >> 16) & 1u);
    return (unsigned short)(u >> 16);
}

// Hb[b][d] = bf16(relu(W[d][x[b,0]] + W[d][x[b,1]]))
// W is [D, P] row-major; the gather is strided (each lane its own line) but
// only 1M useful elements total -> a few us, L2/L3 absorbs.
__global__ void prep_hidden_kernel(const int* __restrict__ x,
                                   const float* __restrict__ W,
                                   unsigned short* __restrict__ Hb) {
    const int b = (blockIdx.x << 1) + (threadIdx.x >> 7);
    const int d = threadIdx.x & 127;
    const int i0 = x[2 * b];
    const int i1 = x[2 * b + 1];
    float h = W[(size_t)d * PP + i0] + W[(size_t)d * PP + i1];
    h = h > 0.0f ? h : 0.0f;
    Hb[(b << 7) + d] = f2bf(h);
}

// Vb = bf16(V), same [P, D] row-major layout.
__global__ void prep_v_kernel(const float* __restrict__ V,
                              unsigned short* __restrict__ Vb) {
    const int i = (blockIdx.x * 256 + threadIdx.x) << 2;
    const float4 v = *reinterpret_cast<const float4*>(V + i);
    ushort4 o;
    o.x = f2bf(v.x); o.y = f2bf(v.y); o.z = f2bf(v.z); o.w = f2bf(v.w);
    *reinterpret_cast<ushort4*>(Vb + i) = o;
}

// out[b][p] = sum_k Hb[b][k] * Vb[p][k]
// MFMA roles: M = p (from Vb), N = b (from Hb), K = d. No LDS: both operands
// fragment-loaded directly from global (L2/L3-hot: Vb 8MB, Hb 1MB).
// Per wave: 64x64 output tile, 4x4 subtiles of 16x16, K=128 in 4 steps of 32.
// A-frag layout: A[m = lane&15][k = (lane>>4)*8 + j]   (verified m118-m122)
// B-frag layout: B[k = (lane>>4)*8 + j][n = lane&15]
// C/D layout:    D[m = (lane>>4)*4 + reg][n = lane&15] (verified m89/m91)
//  -> reg axis = 4 consecutive p at fixed b -> float4 store along output row.
__global__ void gemm_kernel(const unsigned short* __restrict__ Vb,
                            const unsigned short* __restrict__ Hb,
                            float* __restrict__ out) {
    const int wid  = (blockIdx.x << 2) + (threadIdx.x >> 6);
    const int lane = threadIdx.x & 63;
    const int bt = wid & 63;   // 64 b-tiles of 64 (fast axis: p-tile reuse across XCDs)
    const int pt = wid >> 6;   // 500 p-tiles of 64
    const int col = lane & 15; // A row (p) / B col (b) index within 16
    const int kq  = lane >> 4; // 0..3

    const int p0 = pt << 6;
    const int b0 = bt << 6;

    const unsigned short* Abase = Vb + (p0 + col) * DD + (kq << 3);
    const unsigned short* Bbase = Hb + (b0 + col) * DD + (kq << 3);

    f32x4 acc[4][4];
    const f32x4 zero = {0.0f, 0.0f, 0.0f, 0.0f};
    #pragma unroll
    for (int i = 0; i < 4; ++i)
        #pragma unroll
        for (int j = 0; j < 4; ++j)
            acc[i][j] = zero;

    #pragma unroll
    for (int ks = 0; ks < 4; ++ks) {
        bf16x8 a[4], bb[4];
        #pragma unroll
        for (int i = 0; i < 4; ++i)
            a[i] = *reinterpret_cast<const bf16x8*>(Abase + i * 16 * DD + ks * 32);
        #pragma unroll
        for (int j = 0; j < 4; ++j)
            bb[j] = *reinterpret_cast<const bf16x8*>(Bbase + j * 16 * DD + ks * 32);
        #pragma unroll
        for (int i = 0; i < 4; ++i)
            #pragma unroll
            for (int j = 0; j < 4; ++j)
                acc[i][j] = __builtin_amdgcn_mfma_f32_16x16x32_bf16(
                    a[i], bb[j], acc[i][j], 0, 0, 0);
    }

    // store: b = b0 + j*16 + col (row), p = p0 + i*16 + kq*4 + r (contiguous)
    #pragma unroll
    for (int j = 0; j < 4; ++j) {
        float* row = out + (size_t)(b0 + (j << 4) + col) * PP + p0 + (kq << 2);
        #pragma unroll
        for (int i = 0; i < 4; ++i)
            *reinterpret_cast<f32x4*>(row + (i << 4)) = acc[i][j];
    }
}

extern "C" void kernel_launch(void* const* d_in, const int* in_sizes, int n_in,
                              void* d_out, int out_size, void* d_ws, size_t ws_size,
                              hipStream_t stream) {
    const int*   x = (const int*)d_in[0];
    const float* W = (const float*)d_in[1];
    const float* V = (const float*)d_in[2];
    float* out = (float*)d_out;

    // workspace: Hb [4096*128] bf16 (1 MB), then Vb [32000*128] bf16 (8 MB)
    unsigned short* Hb = (unsigned short*)d_ws;
    unsigned short* Vb = Hb + (size_t)BBATCH * DD;

    prep_hidden_kernel<<<BBATCH / 2, 256, 0, stream>>>(x, W, Hb);
    prep_v_kernel<<<(PP * DD) / (4 * 256), 256, 0, stream>>>(V, Vb);
    // 500 p-tiles * 64 b-tiles = 32000 wave-tiles / 4 waves per block
    gemm_kernel<<<8000, 256, 0, stream>>>(Vb, Hb, out);
}